// Round 7
// baseline (315.895 us; speedup 1.0000x reference)
//
#include <hip/hip_runtime.h>

// Problem constants (fixed by the reference)
constexpr int BATCH  = 32;
constexpr int TIME   = 1024;
constexpr int IN_DIM = 512;
constexpr int HIDDEN = 512;

constexpr int GM = BATCH * TIME;   // 32768  (GEMM M)
constexpr int GN = HIDDEN;         // 512    (GEMM N)
constexpr int GK = IN_DIM;         // 512    (GEMM K)

// ---------------- Phase 1: fp32 SGEMM with bias ----------------
// 128x128x16, 256 threads, 8x8 microtile, BOTH operands via LDS.
// Champion config (203-208us, VALUBusy 68%, VGPR 52, 8 blocks/CU max TLP).
// KEEP VERBATIM — 10 rounds of variants all regressed.
constexpr int BM = 128;
constexpr int BN = 128;
constexpr int BK = 16;
constexpr int LDAs = BM + 4;   // padded (2-way LDS alias only = free)
constexpr int LDBs = BN + 4;

__global__ __launch_bounds__(256) void sgemm_bias_kernel(
    const float* __restrict__ A,     // [GM, GK]
    const float* __restrict__ B,     // [GK, GN]
    const float* __restrict__ bias,  // [GN]
    float* __restrict__ C)           // [GM, GN]
{
    __shared__ __align__(16) float As[BK * LDAs];
    __shared__ __align__(16) float Bs[BK * LDBs];

    const int tid = threadIdx.x;           // 0..255
    const int bm  = blockIdx.x * BM;       // M-tile (256): same-A blocks are
    const int bn  = blockIdx.y * BN;       // 256 apart -> same XCD (L2 reuse)

    const int w    = tid >> 6;
    const int lane = tid & 63;
    const int row0 = (w >> 1) * 64 + (lane >> 3) * 8;
    const int col0 = (w & 1)  * 64 + (lane & 7)  * 8;

    const int ar0 = tid >> 2;              // A row for quad 0 (0..63), +64
    const int ac  = (tid & 3) << 2;        // A col within K-tile (0..12)
    const int br0 = tid >> 5;              // B row for quad 0 (0..7), +8
    const int bc  = (tid & 31) << 2;       // B col within N-tile (0..124)

    float acc[8][8];
    #pragma unroll
    for (int i = 0; i < 8; ++i)
        #pragma unroll
        for (int j = 0; j < 8; ++j) acc[i][j] = 0.0f;

    #pragma unroll 1
    for (int k0 = 0; k0 < GK; k0 += BK) {
        float4 va0 = *reinterpret_cast<const float4*>(A + (size_t)(bm + ar0) * GK + k0 + ac);
        float4 va1 = *reinterpret_cast<const float4*>(A + (size_t)(bm + ar0 + 64) * GK + k0 + ac);
        float4 vb0 = *reinterpret_cast<const float4*>(B + (size_t)(k0 + br0) * GN + bn + bc);
        float4 vb1 = *reinterpret_cast<const float4*>(B + (size_t)(k0 + br0 + 8) * GN + bn + bc);

        __syncthreads();   // previous tile's compute done before overwrite

        As[(ac + 0) * LDAs + ar0] = va0.x;
        As[(ac + 1) * LDAs + ar0] = va0.y;
        As[(ac + 2) * LDAs + ar0] = va0.z;
        As[(ac + 3) * LDAs + ar0] = va0.w;
        As[(ac + 0) * LDAs + ar0 + 64] = va1.x;
        As[(ac + 1) * LDAs + ar0 + 64] = va1.y;
        As[(ac + 2) * LDAs + ar0 + 64] = va1.z;
        As[(ac + 3) * LDAs + ar0 + 64] = va1.w;
        *reinterpret_cast<float4*>(&Bs[br0 * LDBs + bc]) = vb0;
        *reinterpret_cast<float4*>(&Bs[(br0 + 8) * LDBs + bc]) = vb1;

        __syncthreads();

        #pragma unroll
        for (int kk = 0; kk < BK; ++kk) {
            const float4 a0 = *reinterpret_cast<const float4*>(&As[kk * LDAs + row0]);
            const float4 a1 = *reinterpret_cast<const float4*>(&As[kk * LDAs + row0 + 4]);
            const float4 b0 = *reinterpret_cast<const float4*>(&Bs[kk * LDBs + col0]);
            const float4 b1 = *reinterpret_cast<const float4*>(&Bs[kk * LDBs + col0 + 4]);
            const float arr[8] = {a0.x, a0.y, a0.z, a0.w, a1.x, a1.y, a1.z, a1.w};
            const float brr[8] = {b0.x, b0.y, b0.z, b0.w, b1.x, b1.y, b1.z, b1.w};
            #pragma unroll
            for (int i = 0; i < 8; ++i)
                #pragma unroll
                for (int j = 0; j < 8; ++j)
                    acc[i][j] = fmaf(arr[i], brr[j], acc[i][j]);
        }
    }

    // ---- epilogue: add bias (separate fp32 add, like numpy), store ----
    #pragma unroll
    for (int i = 0; i < 8; ++i) {
        const size_t r = (size_t)(bm + row0 + i);
        #pragma unroll
        for (int j = 0; j < 8; j += 4) {
            float4 v;
            v.x = __fadd_rn(acc[i][j + 0], bias[bn + col0 + j + 0]);
            v.y = __fadd_rn(acc[i][j + 1], bias[bn + col0 + j + 1]);
            v.z = __fadd_rn(acc[i][j + 2], bias[bn + col0 + j + 2]);
            v.w = __fadd_rn(acc[i][j + 3], bias[bn + col0 + j + 3]);
            *reinterpret_cast<float4*>(&C[r * GN + bn + col0 + j]) = v;
        }
    }
}

// ---------------- Phase 2: LIF scan v4 — row-co-located mapping ----------
// R5 post-mortem: ring-DMA (87us), depth-2 (95us), depth-4 (93us) all tie
// => shared bottleneck is the ACCESS PATTERN, not protocol or depth.
// All three mapped 1 wave -> 64-h column: every load/store touches 256B
// of a 2KB row, and the 8 waves sharing a row sit on 8 different CUs
// with uncorrelated timing -> each DRAM row activated ~8x (both streams)
// -> measured ~1.4 TB/s vs 6.3 TB/s for 1KB-granule copy (m13).
// v4: SAME code, different mapping. 64 blocks x 256 threads; a block's
// 4 waves cover h in [half*256, half*256+256) for one b -> 1KB of each
// row issued back-to-back from one CU (m13's granule). Chain arithmetic
// bit-identical; only blk->(b,h0) decomposition changes.
// R6 crashed: kernel geometry is 64 blocks but launch said 256 -> OOB.
// R7 fixes the GRID ONLY (<<<64, 256>>>). Kernel code unchanged.
constexpr int SCH  = 32;             // timesteps per chunk
constexpr int NCHK = TIME / SCH;     // 32 chunks

#define LOAD_CHUNK(buf, c)                                              \
    {                                                                   \
        const float* p_ = g0 + (size_t)(c) * SCH * HIDDEN;              \
        _Pragma("unroll")                                               \
        for (int u = 0; u < SCH; ++u)                                   \
            buf[u] = p_[(size_t)u * HIDDEN];                            \
    }

#define PROC_CHUNK(buf, c)                                              \
    {                                                                   \
        _Pragma("unroll")                                               \
        for (int u = 0; u < SCH; ++u) {                                 \
            s = __fadd_rn(__fmul_rn(as, s), buf[u]);                    \
            v = __fadd_rn(__fmul_rn(am, v), s);                         \
            const float o_ = (v > 1.0f) ? 1.0f : 0.0f;                  \
            v = __fsub_rn(v, o_);                                       \
            ob[u] = o_;                                                 \
        }                                                               \
        float* q_ = o0 + (size_t)(c) * SCH * HIDDEN;                    \
        _Pragma("unroll")                                               \
        for (int u = 0; u < SCH; ++u)                                   \
            q_[(size_t)u * HIDDEN] = ob[u];                             \
    }

__global__ __launch_bounds__(256) void lif_scan_v4(
    const float* __restrict__ I,   // [B, T, H]
    float* __restrict__ O)         // [B, T, H]
{
    const int blk  = blockIdx.x;           // 0..63
    const int b    = blk >> 1;             // 2 blocks per batch row
    const int wave = threadIdx.x >> 6;     // 0..3
    const int lane = threadIdx.x & 63;
    const int h0   = (blk & 1) * 256 + wave * 64;
    const size_t base = (size_t)b * TIME * HIDDEN + h0 + lane;
    const float* g0 = I + base;
    float*       o0 = O + base;

    // exp(-0.05), exp(-0.2) correctly rounded fp32 (match np.exp)
    const float am = 0.95122942450071400910f;
    const float as = 0.81873075307798185867f;
    float v = 0.0f, s = 0.0f;

    float xA[SCH], xB[SCH], xC[SCH], xD[SCH], ob[SCH];

    // prologue: request 4 chunks (128 loads; HW caps outstanding at ~63)
    LOAD_CHUNK(xA, 0)
    LOAD_CHUNK(xB, 1)
    LOAD_CHUNK(xC, 2)
    LOAD_CHUNK(xD, 3)

    #pragma unroll 1
    for (int c = 0; c < NCHK; c += 4) {
        PROC_CHUNK(xA, c)
        if (c + 4 < NCHK) LOAD_CHUNK(xA, c + 4)
        PROC_CHUNK(xB, c + 1)
        if (c + 5 < NCHK) LOAD_CHUNK(xB, c + 5)
        PROC_CHUNK(xC, c + 2)
        if (c + 6 < NCHK) LOAD_CHUNK(xC, c + 6)
        PROC_CHUNK(xD, c + 3)
        if (c + 7 < NCHK) LOAD_CHUNK(xD, c + 7)
    }
}

extern "C" void kernel_launch(void* const* d_in, const int* in_sizes, int n_in,
                              void* d_out, int out_size, void* d_ws, size_t ws_size,
                              hipStream_t stream) {
    const float* spikes = (const float*)d_in[0];   // [32, 1024, 512]
    const float* W      = (const float*)d_in[1];   // [512, 512]
    const float* bias   = (const float*)d_in[2];   // [512]
    float* out  = (float*)d_out;                   // [32, 1024, 512]
    float* I_in = (float*)d_ws;                    // 64 MiB scratch

    dim3 g1(GM / BM, GN / BN);                     // (256, 4)
    sgemm_bias_kernel<<<g1, 256, 0, stream>>>(spikes, W, bias, I_in);

    lif_scan_v4<<<BATCH * 2, 256, 0, stream>>>(I_in, out);   // 64 blocks
}

// Round 8
// 312.564 us; speedup vs baseline: 1.0107x; 1.0107x over previous
//
#include <hip/hip_runtime.h>

// Problem constants (fixed by the reference)
constexpr int BATCH  = 32;
constexpr int TIME   = 1024;
constexpr int IN_DIM = 512;
constexpr int HIDDEN = 512;

constexpr int GM = BATCH * TIME;   // 32768  (GEMM M)
constexpr int GN = HIDDEN;         // 512    (GEMM N)
constexpr int GK = IN_DIM;         // 512    (GEMM K)

// ---------------- Phase 1: fp32 SGEMM with bias ----------------
// 128x128x16, 256 threads, 8x8 microtile, BOTH operands via LDS.
// Champion config (203-208us, VALUBusy 68%, VGPR 52, 8 blocks/CU max TLP).
// KEEP VERBATIM except the epilogue C-addressing (R8: blocked layout).
constexpr int BM = 128;
constexpr int BN = 128;
constexpr int BK = 16;
constexpr int LDAs = BM + 4;   // padded (2-way LDS alias only = free)
constexpr int LDBs = BN + 4;

// R8: intermediate layout I2[b][hg][t][hl]  (hg = h>>6, hl = h&63).
// Scan wave (b,hg) then owns ONE CONTIGUOUS 256KB region walked
// sequentially in t -> kills the 2KB stride shared by all four tied
// scan variants (87/95/93/95us). Output O stays [B,T,H] (fixed format).

__global__ __launch_bounds__(256) void sgemm_bias_kernel(
    const float* __restrict__ A,     // [GM, GK]
    const float* __restrict__ B,     // [GK, GN]
    const float* __restrict__ bias,  // [GN]
    float* __restrict__ C2)          // I2[b][hg][t][hl]
{
    __shared__ __align__(16) float As[BK * LDAs];
    __shared__ __align__(16) float Bs[BK * LDBs];

    const int tid = threadIdx.x;           // 0..255
    const int bm  = blockIdx.x * BM;       // M-tile (256): same-A blocks are
    const int bn  = blockIdx.y * BN;       // 256 apart -> same XCD (L2 reuse)

    const int w    = tid >> 6;
    const int lane = tid & 63;
    const int row0 = (w >> 1) * 64 + (lane >> 3) * 8;
    const int col0 = (w & 1)  * 64 + (lane & 7)  * 8;

    const int ar0 = tid >> 2;              // A row for quad 0 (0..63), +64
    const int ac  = (tid & 3) << 2;        // A col within K-tile (0..12)
    const int br0 = tid >> 5;              // B row for quad 0 (0..7), +8
    const int bc  = (tid & 31) << 2;       // B col within N-tile (0..124)

    float acc[8][8];
    #pragma unroll
    for (int i = 0; i < 8; ++i)
        #pragma unroll
        for (int j = 0; j < 8; ++j) acc[i][j] = 0.0f;

    #pragma unroll 1
    for (int k0 = 0; k0 < GK; k0 += BK) {
        float4 va0 = *reinterpret_cast<const float4*>(A + (size_t)(bm + ar0) * GK + k0 + ac);
        float4 va1 = *reinterpret_cast<const float4*>(A + (size_t)(bm + ar0 + 64) * GK + k0 + ac);
        float4 vb0 = *reinterpret_cast<const float4*>(B + (size_t)(k0 + br0) * GN + bn + bc);
        float4 vb1 = *reinterpret_cast<const float4*>(B + (size_t)(k0 + br0 + 8) * GN + bn + bc);

        __syncthreads();   // previous tile's compute done before overwrite

        As[(ac + 0) * LDAs + ar0] = va0.x;
        As[(ac + 1) * LDAs + ar0] = va0.y;
        As[(ac + 2) * LDAs + ar0] = va0.z;
        As[(ac + 3) * LDAs + ar0] = va0.w;
        As[(ac + 0) * LDAs + ar0 + 64] = va1.x;
        As[(ac + 1) * LDAs + ar0 + 64] = va1.y;
        As[(ac + 2) * LDAs + ar0 + 64] = va1.z;
        As[(ac + 3) * LDAs + ar0 + 64] = va1.w;
        *reinterpret_cast<float4*>(&Bs[br0 * LDBs + bc]) = vb0;
        *reinterpret_cast<float4*>(&Bs[(br0 + 8) * LDBs + bc]) = vb1;

        __syncthreads();

        #pragma unroll
        for (int kk = 0; kk < BK; ++kk) {
            const float4 a0 = *reinterpret_cast<const float4*>(&As[kk * LDAs + row0]);
            const float4 a1 = *reinterpret_cast<const float4*>(&As[kk * LDAs + row0 + 4]);
            const float4 b0 = *reinterpret_cast<const float4*>(&Bs[kk * LDBs + col0]);
            const float4 b1 = *reinterpret_cast<const float4*>(&Bs[kk * LDBs + col0 + 4]);
            const float arr[8] = {a0.x, a0.y, a0.z, a0.w, a1.x, a1.y, a1.z, a1.w};
            const float brr[8] = {b0.x, b0.y, b0.z, b0.w, b1.x, b1.y, b1.z, b1.w};
            #pragma unroll
            for (int i = 0; i < 8; ++i)
                #pragma unroll
                for (int j = 0; j < 8; ++j)
                    acc[i][j] = fmaf(arr[i], brr[j], acc[i][j]);
        }
    }

    // ---- epilogue: add bias (separate fp32 add, like numpy), store to
    // blocked layout I2[b][hg][t][hl]. bm%1024+127 < 1024 so the whole
    // tile is one batch (bb uniform); float4 stays inside one hg block
    // since (col0+j)%64 <= 60.
    const int bb = bm >> 10;               // batch index of this tile
    const int t0 = bm & 1023;              // tile base t within batch
    #pragma unroll
    for (int i = 0; i < 8; ++i) {
        const int t = t0 + row0 + i;
        #pragma unroll
        for (int j = 0; j < 8; j += 4) {
            const int h  = bn + col0 + j;
            const int hg = h >> 6;
            const int hl = h & 63;
            float4 v;
            v.x = __fadd_rn(acc[i][j + 0], bias[h + 0]);
            v.y = __fadd_rn(acc[i][j + 1], bias[h + 1]);
            v.z = __fadd_rn(acc[i][j + 2], bias[h + 2]);
            v.w = __fadd_rn(acc[i][j + 3], bias[h + 3]);
            *reinterpret_cast<float4*>(
                &C2[((size_t)(bb * 8 + hg) * TIME + t) * 64 + hl]) = v;
        }
    }
}

// ---------------- Phase 2: LIF scan v5 — sequential-stream reads ----------
// Identical depth-4 register pipeline to v3 (93us) EXCEPT the input is the
// blocked layout: wave (b,hg) reads its contiguous 256KB region with
// back-to-back 256B lines (load stride 64 floats instead of 512).
// Clean A/B on the 2KB-stride theory: only the read pattern changes.
// Arithmetic bit-identical: separate __fmul_rn/__fadd_rn, exact constants.
constexpr int SCH  = 32;             // timesteps per chunk
constexpr int NCHK = TIME / SCH;     // 32 chunks

#define LOAD_CHUNK(buf, c)                                              \
    {                                                                   \
        const float* p_ = g0 + (size_t)(c) * SCH * 64;                  \
        _Pragma("unroll")                                               \
        for (int u = 0; u < SCH; ++u)                                   \
            buf[u] = p_[(size_t)u * 64];                                \
    }

#define PROC_CHUNK(buf, c)                                              \
    {                                                                   \
        _Pragma("unroll")                                               \
        for (int u = 0; u < SCH; ++u) {                                 \
            s = __fadd_rn(__fmul_rn(as, s), buf[u]);                    \
            v = __fadd_rn(__fmul_rn(am, v), s);                         \
            const float o_ = (v > 1.0f) ? 1.0f : 0.0f;                  \
            v = __fsub_rn(v, o_);                                       \
            ob[u] = o_;                                                 \
        }                                                               \
        float* q_ = o0 + (size_t)(c) * SCH * HIDDEN;                    \
        _Pragma("unroll")                                               \
        for (int u = 0; u < SCH; ++u)                                   \
            q_[(size_t)u * HIDDEN] = ob[u];                             \
    }

__global__ __launch_bounds__(64) void lif_scan_v5(
    const float* __restrict__ I2,  // [B][8][T][64] blocked
    float* __restrict__ O)         // [B, T, H]
{
    const int sb   = blockIdx.x;           // 0..255
    const int b    = sb >> 3;              // 8 h-groups per batch
    const int hg   = sb & 7;
    const int lane = threadIdx.x;          // 0..63
    const float* g0 = I2 + (size_t)sb * TIME * 64 + lane;  // contiguous region
    float*       o0 = O + (size_t)b * TIME * HIDDEN + hg * 64 + lane;

    // exp(-0.05), exp(-0.2) correctly rounded fp32 (match np.exp)
    const float am = 0.95122942450071400910f;
    const float as = 0.81873075307798185867f;
    float v = 0.0f, s = 0.0f;

    float xA[SCH], xB[SCH], xC[SCH], xD[SCH], ob[SCH];

    // prologue: request 4 chunks
    LOAD_CHUNK(xA, 0)
    LOAD_CHUNK(xB, 1)
    LOAD_CHUNK(xC, 2)
    LOAD_CHUNK(xD, 3)

    #pragma unroll 1
    for (int c = 0; c < NCHK; c += 4) {
        PROC_CHUNK(xA, c)
        if (c + 4 < NCHK) LOAD_CHUNK(xA, c + 4)
        PROC_CHUNK(xB, c + 1)
        if (c + 5 < NCHK) LOAD_CHUNK(xB, c + 5)
        PROC_CHUNK(xC, c + 2)
        if (c + 6 < NCHK) LOAD_CHUNK(xC, c + 6)
        PROC_CHUNK(xD, c + 3)
        if (c + 7 < NCHK) LOAD_CHUNK(xD, c + 7)
    }
}

extern "C" void kernel_launch(void* const* d_in, const int* in_sizes, int n_in,
                              void* d_out, int out_size, void* d_ws, size_t ws_size,
                              hipStream_t stream) {
    const float* spikes = (const float*)d_in[0];   // [32, 1024, 512]
    const float* W      = (const float*)d_in[1];   // [512, 512]
    const float* bias   = (const float*)d_in[2];   // [512]
    float* out  = (float*)d_out;                   // [32, 1024, 512]
    float* I2   = (float*)d_ws;                    // 64 MiB scratch (blocked)

    dim3 g1(GM / BM, GN / BN);                     // (256, 4)
    sgemm_bias_kernel<<<g1, 256, 0, stream>>>(spikes, W, bias, I2);

    lif_scan_v5<<<BATCH * HIDDEN / 64, 64, 0, stream>>>(I2, out);  // 256 blocks
}